// Round 5
// baseline (253.436 us; speedup 1.0000x reference)
//
#include <hip/hip_runtime.h>
#include <stdint.h>

#define LOG2E 1.44269504088896340736f

typedef __attribute__((ext_vector_type(8))) short short8;
typedef __attribute__((ext_vector_type(4))) float float4v;

typedef const __attribute__((address_space(1))) unsigned int gu32;
typedef __attribute__((address_space(3))) unsigned int lu32;

__device__ __forceinline__ void async16(const unsigned short* g, unsigned short* l){
  __builtin_amdgcn_global_load_lds((gu32*)g, (lu32*)l, 16, 0, 0);
}

__device__ __forceinline__ unsigned short f2bf(float f){
  union { float f; unsigned int u; } v; v.f = f;
  unsigned int u = v.u;
  return (unsigned short)((u + 0x7FFFu + ((u >> 16) & 1u)) >> 16);
}
// pack two non-negative floats to bf16 pair (round-to-nearest, no tie-even)
__device__ __forceinline__ unsigned int pkbf(float a, float b){
  union { float f; unsigned int u; } ua, ub; ua.f=a; ub.f=b;
  return ((ua.u + 0x8000u) >> 16) | ((ub.u + 0x8000u) & 0xFFFF0000u);
}

// ---------------- convert x: fp32 -> bf16, 8 elems/thread ----------------
__global__ void convert_x_kernel(const float* __restrict__ x, unsigned short* __restrict__ xb){
  int t = blockIdx.x * 256 + threadIdx.x;
  const float4v* xp = (const float4v*)x;
  float4v a = xp[2*t], b = xp[2*t+1];
  short8 o;
  o[0]=(short)f2bf(a[0]); o[1]=(short)f2bf(a[1]); o[2]=(short)f2bf(a[2]); o[3]=(short)f2bf(a[3]);
  o[4]=(short)f2bf(b[0]); o[5]=(short)f2bf(b[1]); o[6]=(short)f2bf(b[2]); o[7]=(short)f2bf(b[3]);
  ((short8*)xb)[t] = o;
}

// ---------------- transpose weights: W[k][n] fp32 -> WT[n][k] bf16 ----------------
__global__ void transpose_w_kernel(const float* __restrict__ Wq, const float* __restrict__ Wk,
                                   const float* __restrict__ Wv, const float* __restrict__ Wo,
                                   unsigned short* __restrict__ wqkvT, unsigned short* __restrict__ woT){
  __shared__ float tileS[64][68];
  int mat = blockIdx.x >> 8, tile = blockIdx.x & 255;
  int tk = tile >> 4, tn = tile & 15;
  const float* W = (mat==0)?Wq:(mat==1)?Wk:(mat==2)?Wv:Wo;
  int k0 = tk*64, n0 = tn*64;
  int tid = threadIdx.x;
  #pragma unroll
  for (int it=0; it<4; ++it){
    int idx = tid + it*256;
    int r = idx >> 4, c4 = idx & 15;
    float4v v = *(const float4v*)&W[(uint64_t)(k0+r)*1024 + n0 + c4*4];
    tileS[r][c4*4+0]=v[0]; tileS[r][c4*4+1]=v[1]; tileS[r][c4*4+2]=v[2]; tileS[r][c4*4+3]=v[3];
  }
  __syncthreads();
  unsigned short* dst; int nbase;
  if (mat<3){ dst = wqkvT; nbase = mat*1024 + n0; } else { dst = woT; nbase = n0; }
  #pragma unroll
  for (int it=0; it<2; ++it){
    int idx = tid + it*256;
    int n = idx >> 3, g = idx & 7;
    short8 o;
    #pragma unroll
    for (int j=0;j<8;++j) o[j] = (short)f2bf(tileS[g*8+j][n]);
    *(short8*)&dst[(uint64_t)(nbase+n)*1024 + k0 + g*8] = o;
  }
}

// ---------------- transpose V: [bh][l][d] -> [bh][d][l] bf16 ----------------
__global__ void transpose_v_kernel(const unsigned short* __restrict__ v, unsigned short* __restrict__ vt){
  __shared__ __attribute__((aligned(16))) unsigned short t[64][72];
  int bh = blockIdx.x >> 5, lt = blockIdx.x & 31;
  int l0 = lt*64, tid = threadIdx.x;
  #pragma unroll
  for (int it=0; it<2; ++it){
    int idx = tid + it*256;
    int l = idx >> 3, g = idx & 7;
    short8 x = *(const short8*)&v[((uint64_t)bh*2048 + l0 + l)*64 + g*8];
    *(short8*)&t[l][g*8] = x;
  }
  __syncthreads();
  #pragma unroll
  for (int it=0; it<2; ++it){
    int idx = tid + it*256;
    int d = idx >> 3, g = idx & 7;
    short8 o;
    #pragma unroll
    for (int j=0;j<8;++j) o[j] = (short)t[g*8+j][d];
    *(short8*)&vt[((uint64_t)bh*64 + d)*2048 + l0 + g*8] = o;
  }
}

// ---------------- GEMM: C[M][N] = A[M][1024] * BT[N][1024]^T, bf16 MFMA ----------------
// 1-D grid, id -> (by = id & 63, bx = id >> 6): XCD = by%8 invariant.
// EPI 0: bias (+Q scale), bf16 tile -> LDS repack -> 8 coalesced dwordx4 per-head stores.
// EPI 1: bias, fp32 tile -> LDS repack (2 halves) -> 8 coalesced dwordx4 stores per half.
template<int EPI>
__global__ __launch_bounds__(256, 2) void gemm_kernel(
    const unsigned short* __restrict__ A, const unsigned short* __restrict__ BT,
    const float* __restrict__ bias0, const float* __restrict__ bias1, const float* __restrict__ bias2,
    unsigned short* __restrict__ oq, unsigned short* __restrict__ ok,
    unsigned short* __restrict__ ov, float* __restrict__ of)
{
  __shared__ __attribute__((aligned(16))) unsigned short lS[2*128*64];
  unsigned short* lA = lS;
  unsigned short* lB = lS + 128*64;
  const int tid = threadIdx.x, lane = tid & 63, wave = tid >> 6;
  const int wr = wave >> 1, wc = wave & 1;
  const int by = blockIdx.x & 63, bx = blockIdx.x >> 6;
  const int m0 = by * 128, n0 = bx * 128;
  const int c = lane & 15, quad = lane >> 4;
  const float QSCALE = 0.125f * LOG2E;

  float4v acc[4][4];
  #pragma unroll
  for (int i=0;i<4;++i)
    #pragma unroll
    for (int j=0;j<4;++j) acc[i][j] = (float4v){0.f,0.f,0.f,0.f};

  for (int kt = 0; kt < 16; ++kt){
    __syncthreads();
    #pragma unroll
    for (int it=0; it<4; ++it){
      int gl = (wave*4+it)*64 + lane;
      int row = gl >> 3, gp = gl & 7, gs = gp ^ (row & 7);
      async16(&A[(uint64_t)(m0+row)*1024 + kt*64 + gs*8], &lA[gl*8]);
    }
    #pragma unroll
    for (int it=0; it<4; ++it){
      int gl = (wave*4+it)*64 + lane;
      int row = gl >> 3, gp = gl & 7, gs = gp ^ (row & 7);
      async16(&BT[(uint64_t)(n0+row)*1024 + kt*64 + gs*8], &lB[gl*8]);
    }
    __syncthreads();
    #pragma unroll
    for (int kk=0; kk<2; ++kk){
      short8 af[4], bf[4];
      #pragma unroll
      for (int i=0;i<4;++i){
        int row = wr*64 + i*16 + c;
        int g = (quad + kk*4) ^ (row & 7);
        af[i] = *(const short8*)&lA[row*64 + g*8];
      }
      #pragma unroll
      for (int j=0;j<4;++j){
        int row = wc*64 + j*16 + c;
        int g = (quad + kk*4) ^ (row & 7);
        bf[j] = *(const short8*)&lB[row*64 + g*8];
      }
      #pragma unroll
      for (int i=0;i<4;++i)
        #pragma unroll
        for (int j=0;j<4;++j)
          acc[i][j] = __builtin_amdgcn_mfma_f32_16x16x32_bf16(af[i], bf[j], acc[i][j], 0, 0, 0);
    }
  }

  if (EPI == 0){
    const int sel = bx >> 3;                       // 0..7 Q, 8..15 K, 16..23 V
    const int n0l = n0 & 1023;
    const float* bp = (sel==0)?bias0:(sel==1)?bias1:bias2;
    unsigned short* dst = (sel==0)?oq:(sel==1)?ok:ov;
    float bj[4];
    #pragma unroll
    for (int j=0;j<4;++j) bj[j] = bp[n0l + wc*64 + j*16 + c];
    __syncthreads();                               // done reading lS for MFMA
    #pragma unroll
    for (int i=0;i<4;++i){
      #pragma unroll
      for (int r=0;r<4;++r){
        int mloc = wr*64 + i*16 + quad*4 + r;
        #pragma unroll
        for (int j=0;j<4;++j){
          float v = acc[i][j][r] + bj[j];
          if (sel == 0) v *= QSCALE;
          int col = wc*64 + j*16 + c;
          int gg = col >> 3;
          int gs2 = (gg & 8) | ((gg & 7) ^ (mloc & 7));
          lS[mloc*128 + gs2*8 + (col & 7)] = f2bf(v);
        }
      }
    }
    __syncthreads();
    const int h0 = n0l >> 6;
    #pragma unroll
    for (int it=0; it<8; ++it){
      int gl = it*256 + tid;
      int row = gl >> 4, gg = gl & 15;
      int gs2 = (gg & 8) | ((gg & 7) ^ (row & 7));
      short8 w = *(const short8*)&lS[row*128 + gs2*8];
      int m = m0 + row;
      int bb = m >> 11, l = m & 2047;
      int hh = h0 + (gg >> 3);
      *(short8*)&dst[((uint64_t)(bb*16 + hh)*2048 + l)*64 + (gg & 7)*8] = w;
    }
  } else {
    float* lf = (float*)lS;                        // 64 rows x 128 cols fp32 per half
    float bj[4];
    #pragma unroll
    for (int j=0;j<4;++j) bj[j] = bias0[n0 + wc*64 + j*16 + c];
    #pragma unroll
    for (int half=0; half<2; ++half){
      __syncthreads();
      if (wr == half){
        #pragma unroll
        for (int i=0;i<4;++i){
          #pragma unroll
          for (int r=0;r<4;++r){
            int lrow = i*16 + quad*4 + r;
            #pragma unroll
            for (int j=0;j<4;++j){
              int col = wc*64 + j*16 + c;
              int gg = col >> 2;
              int gs2 = (gg & 24) | ((gg & 7) ^ (lrow & 7));
              lf[lrow*128 + gs2*4 + (col & 3)] = acc[i][j][r] + bj[j];
            }
          }
        }
      }
      __syncthreads();
      #pragma unroll
      for (int it=0; it<8; ++it){
        int gl = it*256 + tid;
        int lrow = gl >> 5, gg = gl & 31;
        int gs2 = (gg & 24) | ((gg & 7) ^ (lrow & 7));
        float4v w = *(const float4v*)&lf[lrow*128 + gs2*4];
        *(float4v*)&of[(uint64_t)(m0 + half*64 + lrow)*1024 + n0 + gg*4] = w;
      }
    }
  }
}

// ---------------- flash attention: round-3 K-loop + LDS-repacked output ----------------
__global__ __launch_bounds__(256, 2) void attn_kernel(
    const unsigned short* __restrict__ q, const unsigned short* __restrict__ k,
    const unsigned short* __restrict__ vt, unsigned short* __restrict__ o)
{
  __shared__ __attribute__((aligned(16))) unsigned short lQ[128*64];     // 16 KB
  __shared__ __attribute__((aligned(16))) unsigned short lK[2][64*64];   // 16 KB
  __shared__ __attribute__((aligned(16))) unsigned short lV[2][64*64];   // 16 KB  V^T [d][key]
  __shared__ __attribute__((aligned(16))) unsigned short lP[4][32*64];   // 16 KB  per-wave strips

  const int idx = blockIdx.x;
  const int bh = idx & 63;          // XCD = bh%8 -> per-XCD K/V working set 4MB
  const int qt = 15 - (idx >> 6);   // LPT: longest first
  const int tid = threadIdx.x, lane = tid & 63, wave = tid >> 6;
  const int c = lane & 15, quad = lane >> 4;

  const unsigned short* qh = q  + (uint64_t)bh * (2048*64);
  const unsigned short* kh = k  + (uint64_t)bh * (2048*64);
  const unsigned short* vh = vt + (uint64_t)bh * (64*2048);

  #pragma unroll
  for (int it=0; it<4; ++it){
    int gl = (wave*4+it)*64 + lane;
    int row = gl >> 3, gp = gl & 7, gs = gp ^ (row & 7);
    async16(&qh[(uint64_t)(qt*128 + row)*64 + gs*8], &lQ[gl*8]);
  }
  #pragma unroll
  for (int it=0; it<2; ++it){
    int gl = (wave*2+it)*64 + lane;
    int row = gl >> 3, gp = gl & 7, gs = gp ^ (row & 7);
    async16(&kh[(uint64_t)row*64 + gs*8], &lK[0][gl*8]);
    async16(&vh[(uint64_t)row*2048 + gs*8], &lV[0][gl*8]);
  }

  float4v accO[2][4];
  #pragma unroll
  for (int u=0;u<2;++u)
    #pragma unroll
    for (int t=0;t<4;++t) accO[u][t] = (float4v){0.f,0.f,0.f,0.f};
  float lsum[2] = {0.f, 0.f};
  short8 qf[2][2];

  const int qbase = qt*128 + wave*32;
  const int ktEnd = 2*qt + 1;
  unsigned short* Pw = &lP[wave][0];

  for (int kt = 0; kt <= ktEnd; ++kt){
    __syncthreads();
    const int cb = kt & 1;

    if (kt == 0){
      #pragma unroll
      for (int u=0; u<2; ++u)
        #pragma unroll
        for (int kk=0; kk<2; ++kk){
          int row = wave*32 + u*16 + c;
          int g = (kk*4 + quad) ^ (row & 7);
          qf[u][kk] = *(const short8*)&lQ[row*64 + g*8];
        }
    }
    if (kt < ktEnd){
      const int nb = 1 - cb;
      #pragma unroll
      for (int it=0; it<2; ++it){
        int gl = (wave*2+it)*64 + lane;
        int row = gl >> 3, gp = gl & 7, gs = gp ^ (row & 7);
        async16(&kh[(uint64_t)((kt+1)*64 + row)*64 + gs*8], &lK[nb][gl*8]);
        async16(&vh[(uint64_t)row*2048 + (kt+1)*64 + gs*8], &lV[nb][gl*8]);
      }
    }

    if (kt*64 >= qbase + 32) continue;

    float4v s[2][4];
    #pragma unroll
    for (int u=0;u<2;++u)
      #pragma unroll
      for (int j=0;j<4;++j) s[u][j] = (float4v){0.f,0.f,0.f,0.f};
    #pragma unroll
    for (int kk=0; kk<2; ++kk){
      short8 kf[4];
      #pragma unroll
      for (int j=0;j<4;++j){
        int row = j*16 + c;
        int g = (kk*4 + quad) ^ (row & 7);
        kf[j] = *(const short8*)&lK[cb][row*64 + g*8];
      }
      #pragma unroll
      for (int u=0;u<2;++u)
        #pragma unroll
        for (int j=0;j<4;++j)
          s[u][j] = __builtin_amdgcn_mfma_f32_16x16x32_bf16(kf[j], qf[u][kk], s[u][j], 0, 0, 0);
    }

    const bool needMask = (kt*64 + 63 > qbase);
    #pragma unroll
    for (int u=0;u<2;++u){
      const int qg = qbase + u*16 + c;
      #pragma unroll
      for (int j=0;j<4;++j){
        float p0,p1,p2,p3;
        {
          float4v sv = s[u][j];
          p0 = __builtin_amdgcn_exp2f(sv[0]);
          p1 = __builtin_amdgcn_exp2f(sv[1]);
          p2 = __builtin_amdgcn_exp2f(sv[2]);
          p3 = __builtin_amdgcn_exp2f(sv[3]);
        }
        if (needMask){
          int keyb = kt*64 + j*16 + quad*4;
          if (keyb + 0 > qg) p0 = 0.f;
          if (keyb + 1 > qg) p1 = 0.f;
          if (keyb + 2 > qg) p2 = 0.f;
          if (keyb + 3 > qg) p3 = 0.f;
        }
        lsum[u] += (p0 + p1) + (p2 + p3);
        int row = u*16 + c;
        int g = (2*j + (quad>>1)) ^ (row & 7);
        uint2 w; w.x = pkbf(p0,p1); w.y = pkbf(p2,p3);
        *(uint2*)&Pw[row*64 + g*8 + (quad&1)*4] = w;
      }
    }

    #pragma unroll
    for (int kk=0; kk<2; ++kk){
      short8 bv[4];
      #pragma unroll
      for (int t=0;t<4;++t){
        int row = t*16 + c;
        int g = (kk*4 + quad) ^ (row & 7);
        bv[t] = *(const short8*)&lV[cb][row*64 + g*8];
      }
      #pragma unroll
      for (int u=0;u<2;++u){
        int row = u*16 + c;
        int g = (kk*4 + quad) ^ (row & 7);
        short8 ap = *(const short8*)&Pw[row*64 + g*8];
        #pragma unroll
        for (int t=0;t<4;++t)
          accO[u][t] = __builtin_amdgcn_mfma_f32_16x16x32_bf16(ap, bv[t], accO[u][t], 0, 0, 0);
      }
    }
  }

  #pragma unroll
  for (int u=0;u<2;++u){
    lsum[u] += __shfl_xor(lsum[u], 16, 64);
    lsum[u] += __shfl_xor(lsum[u], 32, 64);
  }

  // normalize into lP (flat 128x64 bf16, swizzled), then coalesced dwordx4 stores
  const int b = bh >> 4, h = bh & 15;
  unsigned short* lPf = &lP[0][0];
  #pragma unroll
  for (int u=0;u<2;++u){
    #pragma unroll
    for (int r=0;r<4;++r){
      float ls = __shfl(lsum[u], quad*4 + r, 64);
      float rinv = 1.0f / ls;
      int mloc = wave*32 + u*16 + quad*4 + r;
      #pragma unroll
      for (int t=0;t<4;++t){
        int col = t*16 + c;
        int gg = col >> 3;
        int gs2 = gg ^ (mloc & 7);
        lPf[mloc*64 + gs2*8 + (col & 7)] = f2bf(accO[u][t][r] * rinv);
      }
    }
  }
  __syncthreads();
  #pragma unroll
  for (int it=0; it<4; ++it){
    int gl = it*256 + tid;
    int row = gl >> 3, gg = gl & 7;
    int gs2 = gg ^ (row & 7);
    short8 w = *(const short8*)&lPf[row*64 + gs2*8];
    uint64_t m = (uint64_t)b*2048 + qt*128 + row;
    *(short8*)&o[m*1024 + h*64 + gg*8] = w;
  }
}

extern "C" void kernel_launch(void* const* d_in, const int* in_sizes, int n_in,
                              void* d_out, int out_size, void* d_ws, size_t ws_size,
                              hipStream_t stream)
{
  (void)in_sizes; (void)n_in; (void)out_size; (void)ws_size;
  const float* x  = (const float*)d_in[0];
  const float* Wq = (const float*)d_in[1];
  const float* bq = (const float*)d_in[2];
  const float* Wk = (const float*)d_in[3];
  const float* bk = (const float*)d_in[4];
  const float* Wv = (const float*)d_in[5];
  const float* bv = (const float*)d_in[6];
  const float* Wo = (const float*)d_in[7];
  const float* bo = (const float*)d_in[8];
  float* out = (float*)d_out;

  char* ws = (char*)d_ws;
  unsigned short* xb    = (unsigned short*)(ws);                     // 16 MB (later reused as V^T)
  unsigned short* wqkvT = (unsigned short*)(ws + (16ull<<20));       // 6 MB
  unsigned short* woT   = (unsigned short*)(ws + (22ull<<20));       // 2 MB
  unsigned short* qb    = (unsigned short*)(ws + (24ull<<20));       // 16 MB
  unsigned short* kb    = (unsigned short*)(ws + (40ull<<20));       // 16 MB
  unsigned short* vb    = (unsigned short*)(ws + (56ull<<20));       // 16 MB (later reused as attn out)
  unsigned short* vtb   = xb;   // x dead after QKV GEMM
  unsigned short* ab    = vb;   // v dead after transpose

  convert_x_kernel<<<4096, 256, 0, stream>>>(x, xb);
  transpose_w_kernel<<<1024, 256, 0, stream>>>(Wq, Wk, Wv, Wo, wqkvT, woT);
  gemm_kernel<0><<<1536, 256, 0, stream>>>(xb, wqkvT, bq, bk, bv, qb, kb, vb, nullptr);
  transpose_v_kernel<<<2048, 256, 0, stream>>>(vb, vtb);
  attn_kernel<<<1024, 256, 0, stream>>>(qb, kb, vtb, ab);
  gemm_kernel<1><<<512, 256, 0, stream>>>(ab, woT, bo, nullptr, nullptr, nullptr, nullptr, nullptr, out);
}

// Round 6
// 247.447 us; speedup vs baseline: 1.0242x; 1.0242x over previous
//
#include <hip/hip_runtime.h>
#include <stdint.h>

#define LOG2E 1.44269504088896340736f

typedef __attribute__((ext_vector_type(8))) short short8;
typedef __attribute__((ext_vector_type(4))) float float4v;

typedef const __attribute__((address_space(1))) unsigned int gu32;
typedef __attribute__((address_space(3))) unsigned int lu32;

__device__ __forceinline__ void async16(const unsigned short* g, unsigned short* l){
  __builtin_amdgcn_global_load_lds((gu32*)g, (lu32*)l, 16, 0, 0);
}

__device__ __forceinline__ unsigned short f2bf(float f){
  union { float f; unsigned int u; } v; v.f = f;
  unsigned int u = v.u;
  return (unsigned short)((u + 0x7FFFu + ((u >> 16) & 1u)) >> 16);
}
// pack two non-negative floats to bf16 pair (round-to-nearest, no tie-even)
__device__ __forceinline__ unsigned int pkbf(float a, float b){
  union { float f; unsigned int u; } ua, ub; ua.f=a; ub.f=b;
  return ((ua.u + 0x8000u) >> 16) | ((ub.u + 0x8000u) & 0xFFFF0000u);
}

// ---------------- convert x: fp32 -> bf16, 8 elems/thread ----------------
__global__ void convert_x_kernel(const float* __restrict__ x, unsigned short* __restrict__ xb){
  int t = blockIdx.x * 256 + threadIdx.x;
  const float4v* xp = (const float4v*)x;
  float4v a = xp[2*t], b = xp[2*t+1];
  short8 o;
  o[0]=(short)f2bf(a[0]); o[1]=(short)f2bf(a[1]); o[2]=(short)f2bf(a[2]); o[3]=(short)f2bf(a[3]);
  o[4]=(short)f2bf(b[0]); o[5]=(short)f2bf(b[1]); o[6]=(short)f2bf(b[2]); o[7]=(short)f2bf(b[3]);
  ((short8*)xb)[t] = o;
}

// ---------------- transpose weights: W[k][n] fp32 -> WT[n][k] bf16 ----------------
__global__ void transpose_w_kernel(const float* __restrict__ Wq, const float* __restrict__ Wk,
                                   const float* __restrict__ Wv, const float* __restrict__ Wo,
                                   unsigned short* __restrict__ wqkvT, unsigned short* __restrict__ woT){
  __shared__ float tileS[64][68];
  int mat = blockIdx.x >> 8, tile = blockIdx.x & 255;
  int tk = tile >> 4, tn = tile & 15;
  const float* W = (mat==0)?Wq:(mat==1)?Wk:(mat==2)?Wv:Wo;
  int k0 = tk*64, n0 = tn*64;
  int tid = threadIdx.x;
  #pragma unroll
  for (int it=0; it<4; ++it){
    int idx = tid + it*256;
    int r = idx >> 4, c4 = idx & 15;
    float4v v = *(const float4v*)&W[(uint64_t)(k0+r)*1024 + n0 + c4*4];
    tileS[r][c4*4+0]=v[0]; tileS[r][c4*4+1]=v[1]; tileS[r][c4*4+2]=v[2]; tileS[r][c4*4+3]=v[3];
  }
  __syncthreads();
  unsigned short* dst; int nbase;
  if (mat<3){ dst = wqkvT; nbase = mat*1024 + n0; } else { dst = woT; nbase = n0; }
  #pragma unroll
  for (int it=0; it<2; ++it){
    int idx = tid + it*256;
    int n = idx >> 3, g = idx & 7;
    short8 o;
    #pragma unroll
    for (int j=0;j<8;++j) o[j] = (short)f2bf(tileS[g*8+j][n]);
    *(short8*)&dst[(uint64_t)(nbase+n)*1024 + k0 + g*8] = o;
  }
}

// ---------------- GEMM: C[M][N] = A[M][1024] * BT[N][1024]^T, bf16 MFMA ----------------
// 1-D grid, id -> (by = id & 63, bx = id >> 6): XCD = by%8 invariant.
// EPI 0: bias (+Q scale); Q/K: bf16 repack -> coalesced per-head stores.
//        V: TRANSPOSED repack -> stores V^T [bh][d][l] directly (transpose_v fused).
// EPI 1: bias, fp32 repack (2 halves) -> coalesced dwordx4 stores.
template<int EPI>
__global__ __launch_bounds__(256, 2) void gemm_kernel(
    const unsigned short* __restrict__ A, const unsigned short* __restrict__ BT,
    const float* __restrict__ bias0, const float* __restrict__ bias1, const float* __restrict__ bias2,
    unsigned short* __restrict__ oq, unsigned short* __restrict__ ok,
    unsigned short* __restrict__ ov, float* __restrict__ of)
{
  __shared__ __attribute__((aligned(16))) unsigned short lS[2*128*64];
  unsigned short* lA = lS;
  unsigned short* lB = lS + 128*64;
  const int tid = threadIdx.x, lane = tid & 63, wave = tid >> 6;
  const int wr = wave >> 1, wc = wave & 1;
  const int by = blockIdx.x & 63, bx = blockIdx.x >> 6;
  const int m0 = by * 128, n0 = bx * 128;
  const int c = lane & 15, quad = lane >> 4;
  const float QSCALE = 0.125f * LOG2E;

  float4v acc[4][4];
  #pragma unroll
  for (int i=0;i<4;++i)
    #pragma unroll
    for (int j=0;j<4;++j) acc[i][j] = (float4v){0.f,0.f,0.f,0.f};

  for (int kt = 0; kt < 16; ++kt){
    __syncthreads();
    #pragma unroll
    for (int it=0; it<4; ++it){
      int gl = (wave*4+it)*64 + lane;
      int row = gl >> 3, gp = gl & 7, gs = gp ^ (row & 7);
      async16(&A[(uint64_t)(m0+row)*1024 + kt*64 + gs*8], &lA[gl*8]);
    }
    #pragma unroll
    for (int it=0; it<4; ++it){
      int gl = (wave*4+it)*64 + lane;
      int row = gl >> 3, gp = gl & 7, gs = gp ^ (row & 7);
      async16(&BT[(uint64_t)(n0+row)*1024 + kt*64 + gs*8], &lB[gl*8]);
    }
    __syncthreads();
    #pragma unroll
    for (int kk=0; kk<2; ++kk){
      short8 af[4], bf[4];
      #pragma unroll
      for (int i=0;i<4;++i){
        int row = wr*64 + i*16 + c;
        int g = (quad + kk*4) ^ (row & 7);
        af[i] = *(const short8*)&lA[row*64 + g*8];
      }
      #pragma unroll
      for (int j=0;j<4;++j){
        int row = wc*64 + j*16 + c;
        int g = (quad + kk*4) ^ (row & 7);
        bf[j] = *(const short8*)&lB[row*64 + g*8];
      }
      #pragma unroll
      for (int i=0;i<4;++i)
        #pragma unroll
        for (int j=0;j<4;++j)
          acc[i][j] = __builtin_amdgcn_mfma_f32_16x16x32_bf16(af[i], bf[j], acc[i][j], 0, 0, 0);
    }
  }

  if (EPI == 0){
    const int sel = bx >> 3;                       // 0..7 Q, 8..15 K, 16..23 V
    const int n0l = n0 & 1023;
    const int h0 = n0l >> 6;
    const int bb = m0 >> 11, l0 = m0 & 2047;
    const float* bp = (sel==0)?bias0:(sel==1)?bias1:bias2;
    float bj[4];
    #pragma unroll
    for (int j=0;j<4;++j) bj[j] = bp[n0l + wc*64 + j*16 + c];
    __syncthreads();                               // done reading lS for MFMA
    if (sel < 2){
      unsigned short* dst = (sel==0)?oq:ok;
      #pragma unroll
      for (int i=0;i<4;++i){
        #pragma unroll
        for (int r=0;r<4;++r){
          int mloc = wr*64 + i*16 + quad*4 + r;
          #pragma unroll
          for (int j=0;j<4;++j){
            float v = acc[i][j][r] + bj[j];
            if (sel == 0) v *= QSCALE;
            int col = wc*64 + j*16 + c;
            int gg = col >> 3;
            int gs2 = (gg & 8) | ((gg & 7) ^ (mloc & 7));
            lS[mloc*128 + gs2*8 + (col & 7)] = f2bf(v);
          }
        }
      }
      __syncthreads();
      #pragma unroll
      for (int it=0; it<8; ++it){
        int gl = it*256 + tid;
        int row = gl >> 4, gg = gl & 15;
        int gs2 = (gg & 8) | ((gg & 7) ^ (row & 7));
        short8 w = *(const short8*)&lS[row*128 + gs2*8];
        int hh = h0 + (gg >> 3);
        *(short8*)&dst[((uint64_t)(bb*16 + hh)*2048 + l0 + row)*64 + (gg & 7)*8] = w;
      }
    } else {
      // V: transposed repack -> store V^T [bh][d][l]
      #pragma unroll
      for (int i=0;i<4;++i){
        #pragma unroll
        for (int r=0;r<4;++r){
          int mloc = wr*64 + i*16 + quad*4 + r;
          int mgg = mloc >> 3;
          #pragma unroll
          for (int j=0;j<4;++j){
            float v = acc[i][j][r] + bj[j];
            int col = wc*64 + j*16 + c;
            int gsT = (mgg & 8) | ((mgg & 7) ^ (col & 7));
            lS[col*128 + gsT*8 + (mloc & 7)] = f2bf(v);
          }
        }
      }
      __syncthreads();
      #pragma unroll
      for (int it=0; it<8; ++it){
        int idx = it*256 + tid;
        int mg = idx & 15, cc = idx >> 4;
        int gsT2 = (mg & 8) | ((mg & 7) ^ (cc & 7));
        short8 w = *(const short8*)&lS[cc*128 + gsT2*8];
        int hh = h0 + (cc >> 6), d = cc & 63;
        *(short8*)&ov[((uint64_t)(bb*16 + hh)*64 + d)*2048 + l0 + mg*8] = w;
      }
    }
  } else {
    float* lf = (float*)lS;                        // 64 rows x 128 cols fp32 per half
    float bj[4];
    #pragma unroll
    for (int j=0;j<4;++j) bj[j] = bias0[n0 + wc*64 + j*16 + c];
    #pragma unroll
    for (int half=0; half<2; ++half){
      __syncthreads();
      if (wr == half){
        #pragma unroll
        for (int i=0;i<4;++i){
          #pragma unroll
          for (int r=0;r<4;++r){
            int lrow = i*16 + quad*4 + r;
            #pragma unroll
            for (int j=0;j<4;++j){
              int col = wc*64 + j*16 + c;
              int gg = col >> 2;
              int gs2 = (gg & 24) | ((gg & 7) ^ (lrow & 7));
              lf[lrow*128 + gs2*4 + (col & 3)] = acc[i][j][r] + bj[j];
            }
          }
        }
      }
      __syncthreads();
      #pragma unroll
      for (int it=0; it<8; ++it){
        int gl = it*256 + tid;
        int lrow = gl >> 5, gg = gl & 31;
        int gs2 = (gg & 24) | ((gg & 7) ^ (lrow & 7));
        float4v w = *(const float4v*)&lf[lrow*128 + gs2*4];
        *(float4v*)&of[(uint64_t)(m0 + half*64 + lrow)*1024 + n0 + gg*4] = w;
      }
    }
  }
}

// ---------------- flash attention round 6 ----------------
// Balanced query->wave mapping: wave w owns rows {u*64 + w*16 .. +15} for u=0,1.
// u=1 sub-tile active every K-iteration; u=0 active for all but the last
// (block-uniform skip) -> no wave idles at the barrier.
__global__ __launch_bounds__(256, 2) void attn_kernel(
    const unsigned short* __restrict__ q, const unsigned short* __restrict__ k,
    const unsigned short* __restrict__ vt, unsigned short* __restrict__ o)
{
  __shared__ __attribute__((aligned(16))) unsigned short lQ[128*64];     // 16 KB
  __shared__ __attribute__((aligned(16))) unsigned short lK[2][64*64];   // 16 KB
  __shared__ __attribute__((aligned(16))) unsigned short lV[2][64*64];   // 16 KB  V^T [d][key]
  __shared__ __attribute__((aligned(16))) unsigned short lP[4][32*64];   // 16 KB  per-wave strips

  const int idx = blockIdx.x;
  const int bh = idx & 63;          // XCD = bh%8 -> per-XCD K/V working set 4MB
  const int qt = 15 - (idx >> 6);   // LPT: longest first
  const int tid = threadIdx.x, lane = tid & 63, wave = tid >> 6;
  const int c = lane & 15, quad = lane >> 4;

  const unsigned short* qh = q  + (uint64_t)bh * (2048*64);
  const unsigned short* kh = k  + (uint64_t)bh * (2048*64);
  const unsigned short* vh = vt + (uint64_t)bh * (64*2048);

  #pragma unroll
  for (int it=0; it<4; ++it){
    int gl = (wave*4+it)*64 + lane;
    int row = gl >> 3, gp = gl & 7, gs = gp ^ (row & 7);
    async16(&qh[(uint64_t)(qt*128 + row)*64 + gs*8], &lQ[gl*8]);
  }
  #pragma unroll
  for (int it=0; it<2; ++it){
    int gl = (wave*2+it)*64 + lane;
    int row = gl >> 3, gp = gl & 7, gs = gp ^ (row & 7);
    async16(&kh[(uint64_t)row*64 + gs*8], &lK[0][gl*8]);
    async16(&vh[(uint64_t)row*2048 + gs*8], &lV[0][gl*8]);
  }

  float4v accO[2][4];
  #pragma unroll
  for (int u=0;u<2;++u)
    #pragma unroll
    for (int t=0;t<4;++t) accO[u][t] = (float4v){0.f,0.f,0.f,0.f};
  float lsum[2] = {0.f, 0.f};
  short8 qf[2][2];

  const int ktEnd = 2*qt + 1;
  unsigned short* Pw = &lP[wave][0];

  for (int kt = 0; kt <= ktEnd; ++kt){
    __syncthreads();
    const int cb = kt & 1;

    if (kt == 0){
      #pragma unroll
      for (int u=0; u<2; ++u)
        #pragma unroll
        for (int kk=0; kk<2; ++kk){
          int row = u*64 + wave*16 + c;
          int g = (kk*4 + quad) ^ (row & 7);
          qf[u][kk] = *(const short8*)&lQ[row*64 + g*8];
        }
    }
    if (kt < ktEnd){
      const int nb = 1 - cb;
      #pragma unroll
      for (int it=0; it<2; ++it){
        int gl = (wave*2+it)*64 + lane;
        int row = gl >> 3, gp = gl & 7, gs = gp ^ (row & 7);
        async16(&kh[(uint64_t)((kt+1)*64 + row)*64 + gs*8], &lK[nb][gl*8]);
        async16(&vh[(uint64_t)row*2048 + (kt+1)*64 + gs*8], &lV[nb][gl*8]);
      }
    }

    const bool doU0 = (kt != ktEnd);   // u=0 queries need all but the last key tile

    // S^T = K * Q^T : key = kt*64 + j*16 + quad*4 + r, query = qt*128 + u*64 + wave*16 + c
    float4v s[2][4];
    #pragma unroll
    for (int u=0;u<2;++u)
      #pragma unroll
      for (int j=0;j<4;++j) s[u][j] = (float4v){0.f,0.f,0.f,0.f};
    #pragma unroll
    for (int kk=0; kk<2; ++kk){
      short8 kf[4];
      #pragma unroll
      for (int j=0;j<4;++j){
        int row = j*16 + c;
        int g = (kk*4 + quad) ^ (row & 7);
        kf[j] = *(const short8*)&lK[cb][row*64 + g*8];
      }
      #pragma unroll
      for (int j=0;j<4;++j)
        s[1][j] = __builtin_amdgcn_mfma_f32_16x16x32_bf16(kf[j], qf[1][kk], s[1][j], 0, 0, 0);
      if (doU0){
        #pragma unroll
        for (int j=0;j<4;++j)
          s[0][j] = __builtin_amdgcn_mfma_f32_16x16x32_bf16(kf[j], qf[0][kk], s[0][j], 0, 0, 0);
      }
    }

    #pragma unroll
    for (int u=0;u<2;++u){
      if (u==0 && !doU0) continue;
      const int qb_u = qt*128 + u*64 + wave*16;
      const bool needMask = (kt*64 + 63 > qb_u);
      const int qg = qb_u + c;
      #pragma unroll
      for (int j=0;j<4;++j){
        float p0,p1,p2,p3;
        {
          float4v sv = s[u][j];
          p0 = __builtin_amdgcn_exp2f(sv[0]);
          p1 = __builtin_amdgcn_exp2f(sv[1]);
          p2 = __builtin_amdgcn_exp2f(sv[2]);
          p3 = __builtin_amdgcn_exp2f(sv[3]);
        }
        if (needMask){
          int keyb = kt*64 + j*16 + quad*4;
          if (keyb + 0 > qg) p0 = 0.f;
          if (keyb + 1 > qg) p1 = 0.f;
          if (keyb + 2 > qg) p2 = 0.f;
          if (keyb + 3 > qg) p3 = 0.f;
        }
        lsum[u] += (p0 + p1) + (p2 + p3);
        int row = u*16 + c;
        int g = (2*j + (quad>>1)) ^ (row & 7);
        uint2 w; w.x = pkbf(p0,p1); w.y = pkbf(p2,p3);
        *(uint2*)&Pw[row*64 + g*8 + (quad&1)*4] = w;
      }
    }

    // O += P * V : A = P (strip row u*16+c <-> query qb_u+c), B = V^T
    #pragma unroll
    for (int kk=0; kk<2; ++kk){
      short8 bv[4];
      #pragma unroll
      for (int t=0;t<4;++t){
        int row = t*16 + c;
        int g = (kk*4 + quad) ^ (row & 7);
        bv[t] = *(const short8*)&lV[cb][row*64 + g*8];
      }
      {
        int row = 16 + c;
        int g = (kk*4 + quad) ^ (row & 7);
        short8 ap = *(const short8*)&Pw[row*64 + g*8];
        #pragma unroll
        for (int t=0;t<4;++t)
          accO[1][t] = __builtin_amdgcn_mfma_f32_16x16x32_bf16(ap, bv[t], accO[1][t], 0, 0, 0);
      }
      if (doU0){
        int row = c;
        int g = (kk*4 + quad) ^ (row & 7);
        short8 ap = *(const short8*)&Pw[row*64 + g*8];
        #pragma unroll
        for (int t=0;t<4;++t)
          accO[0][t] = __builtin_amdgcn_mfma_f32_16x16x32_bf16(ap, bv[t], accO[0][t], 0, 0, 0);
      }
    }
  }

  #pragma unroll
  for (int u=0;u<2;++u){
    lsum[u] += __shfl_xor(lsum[u], 16, 64);
    lsum[u] += __shfl_xor(lsum[u], 32, 64);
  }

  // normalize into lP (flat 128x64 bf16, swizzled), then coalesced dwordx4 stores
  const int b = bh >> 4, h = bh & 15;
  unsigned short* lPf = &lP[0][0];
  #pragma unroll
  for (int u=0;u<2;++u){
    #pragma unroll
    for (int r=0;r<4;++r){
      float ls = __shfl(lsum[u], quad*4 + r, 64);
      float rinv = 1.0f / ls;
      int mloc = u*64 + wave*16 + quad*4 + r;
      #pragma unroll
      for (int t=0;t<4;++t){
        int col = t*16 + c;
        int gg = col >> 3;
        int gs2 = gg ^ (mloc & 7);
        lPf[mloc*64 + gs2*8 + (col & 7)] = f2bf(accO[u][t][r] * rinv);
      }
    }
  }
  __syncthreads();
  #pragma unroll
  for (int it=0; it<4; ++it){
    int gl = it*256 + tid;
    int row = gl >> 3, gg = gl & 7;
    int gs2 = gg ^ (row & 7);
    short8 w = *(const short8*)&lPf[row*64 + gs2*8];
    uint64_t m = (uint64_t)b*2048 + qt*128 + row;
    *(short8*)&o[m*1024 + h*64 + gg*8] = w;
  }
}

extern "C" void kernel_launch(void* const* d_in, const int* in_sizes, int n_in,
                              void* d_out, int out_size, void* d_ws, size_t ws_size,
                              hipStream_t stream)
{
  (void)in_sizes; (void)n_in; (void)out_size; (void)ws_size;
  const float* x  = (const float*)d_in[0];
  const float* Wq = (const float*)d_in[1];
  const float* bq = (const float*)d_in[2];
  const float* Wk = (const float*)d_in[3];
  const float* bk = (const float*)d_in[4];
  const float* Wv = (const float*)d_in[5];
  const float* bv = (const float*)d_in[6];
  const float* Wo = (const float*)d_in[7];
  const float* bo = (const float*)d_in[8];
  float* out = (float*)d_out;

  char* ws = (char*)d_ws;
  unsigned short* xb    = (unsigned short*)(ws);                     // 16 MB (reused as attn out)
  unsigned short* wqkvT = (unsigned short*)(ws + (16ull<<20));       // 6 MB
  unsigned short* woT   = (unsigned short*)(ws + (22ull<<20));       // 2 MB
  unsigned short* qb    = (unsigned short*)(ws + (24ull<<20));       // 16 MB
  unsigned short* kb    = (unsigned short*)(ws + (40ull<<20));       // 16 MB
  unsigned short* vtb   = (unsigned short*)(ws + (56ull<<20));       // 16 MB V^T (written by gemm0)
  unsigned short* ab    = xb;   // x dead after QKV GEMM

  convert_x_kernel<<<4096, 256, 0, stream>>>(x, xb);
  transpose_w_kernel<<<1024, 256, 0, stream>>>(Wq, Wk, Wv, Wo, wqkvT, woT);
  gemm_kernel<0><<<1536, 256, 0, stream>>>(xb, wqkvT, bq, bk, bv, qb, kb, vtb, nullptr);
  attn_kernel<<<1024, 256, 0, stream>>>(qb, kb, vtb, ab);
  gemm_kernel<1><<<512, 256, 0, stream>>>(ab, woT, bo, nullptr, nullptr, nullptr, nullptr, nullptr, out);
}